// Round 6
// baseline (225.528 us; speedup 1.0000x reference)
//
#include <hip/hip_runtime.h>

#define B_SZ 4096
#define N_IN 4096
#define N_CTX 512
#define UNITS 4096
#define RANK 256
#define ZSPLIT 8

typedef __attribute__((ext_vector_type(8))) __bf16 bf16x8;
typedef __attribute__((ext_vector_type(4))) float f32x4;
typedef __attribute__((ext_vector_type(8))) unsigned short ushort8;

__device__ __forceinline__ unsigned short f2bf(float f) {      // RNE (prep only)
    unsigned int u = __float_as_uint(f);
    u += 0x7FFFu + ((u >> 16) & 1u);
    return (unsigned short)(u >> 16);
}
__device__ __forceinline__ unsigned short f2bf_fast(float f) { // round-half-up, 0.5ulp
    return (unsigned short)((__float_as_uint(f) + 0x8000u) >> 16);
}
__device__ __forceinline__ float bf2f(unsigned short h) {
    return __uint_as_float(((unsigned int)h) << 16);
}
__device__ __forceinline__ bf16x8 ldfrag(const unsigned short* p) {
    ushort8 t = *(const ushort8*)p;
    return __builtin_bit_cast(bf16x8, t);
}
__device__ __forceinline__ ushort8 cvt8u(float4 lo, float4 hi) {
    ushort8 t = { f2bf_fast(lo.x), f2bf_fast(lo.y), f2bf_fast(lo.z), f2bf_fast(lo.w),
                  f2bf_fast(hi.x), f2bf_fast(hi.y), f2bf_fast(hi.z), f2bf_fast(hi.w) };
    return t;
}
#define MFMA(a, b, c) __builtin_amdgcn_mfma_f32_16x16x32_bf16((a), (b), (c), 0, 0, 0)

// ---- fused prep: U^T (bf16), W^T (bf16), V convert (bf16) --------------
__global__ void prep(const float* __restrict__ U, const float* __restrict__ W,
                     const float* __restrict__ V,
                     unsigned short* __restrict__ UT, unsigned short* __restrict__ WT,
                     unsigned short* __restrict__ Vb) {
    __shared__ unsigned short t[64][66];
    int bid = blockIdx.x, tid = threadIdx.x;
    if (bid < 288) {
        const float* src; unsigned short* dst; int R, C, rb, cb;
        if (bid < 256) { src = U; dst = UT; R = N_IN; C = RANK; rb = (bid & 63) * 64; cb = (bid >> 6) * 64; }
        else { int b = bid - 256; src = W; dst = WT; R = N_CTX; C = RANK; rb = (b & 7) * 64; cb = (b >> 3) * 64; }
        int r = tid >> 4, c4 = (tid & 15) * 4;
        for (int i = 0; i < 4; i++) {
            float4 v = *(const float4*)(src + (size_t)(rb + r + i * 16) * C + cb + c4);
            t[r + i * 16][c4 + 0] = f2bf(v.x);
            t[r + i * 16][c4 + 1] = f2bf(v.y);
            t[r + i * 16][c4 + 2] = f2bf(v.z);
            t[r + i * 16][c4 + 3] = f2bf(v.w);
        }
        __syncthreads();
        int c = tid >> 3, r8 = (tid & 7) * 8;
        for (int j = 0; j < 2; j++) {
            int cc = c + j * 32;
            ushort8 o;
            for (int k = 0; k < 8; k++) o[k] = t[r8 + k][cc];
            *(ushort8*)(dst + (size_t)(cb + cc) * R + rb + r8) = o;
        }
    } else {
        size_t base = (size_t)(bid - 288) * 2048 + (size_t)tid * 8;
        float4 a = *(const float4*)(V + base);
        float4 b = *(const float4*)(V + base + 4);
        ushort8 o = { f2bf(a.x), f2bf(a.y), f2bf(a.z), f2bf(a.w),
                      f2bf(b.x), f2bf(b.y), f2bf(b.z), f2bf(b.w) };
        *(ushort8*)(Vb + base) = o;
    }
}

// ---- K1: Schi = S*sigmoid(ctx@W+B). B-LDS resident, grid (4,64)=256 blk ----
// 256 thr = 4 waves; wave tile m=16 n=64, K=512
__launch_bounds__(256, 4)
__global__ void k1_chi(const float* __restrict__ ctx, const unsigned short* __restrict__ WT,
                       const float* __restrict__ S, const float* __restrict__ Bb,
                       unsigned short* __restrict__ Schi) {
    __shared__ unsigned short Bs[64 * 512];   // 64 KB
    int tid = threadIdx.x, wv = tid >> 6, lane = tid & 63;
    int ln15 = lane & 15, quad = lane >> 4;
    int n0 = blockIdx.x * 64, mbase = blockIdx.y * 64;
    #pragma unroll
    for (int i = 0; i < 16; i++) {
        int linear = i * 256 + tid;
        int r = linear >> 6, c = linear & 63;
        ushort8 v = *(const ushort8*)(WT + (size_t)(n0 + r) * N_CTX + c * 8);
        *(ushort8*)(Bs + r * 512 + ((c ^ (r & 7)) * 8)) = v;
    }
    __syncthreads();
    int m0 = mbase + wv * 16;
    const float* Xp = ctx + (size_t)(m0 + ln15) * N_CTX + quad * 8;
    f32x4 acc[4] = {};
    float4 a[2][2];
    a[0][0] = *(const float4*)(Xp); a[0][1] = *(const float4*)(Xp + 4);
    #pragma unroll
    for (int kt = 0; kt < 16; kt++) {
        int cur = kt & 1, nxt = cur ^ 1;
        if (kt < 15) {
            int ko = (kt + 1) * 32;
            a[nxt][0] = *(const float4*)(Xp + ko); a[nxt][1] = *(const float4*)(Xp + ko + 4);
        }
        bf16x8 bfr[4];
        int sw8 = ((4 * kt + quad) ^ (ln15 & 7)) * 8;
        #pragma unroll
        for (int j = 0; j < 4; j++) bfr[j] = ldfrag(Bs + (j * 16 + ln15) * 512 + sw8);
        bf16x8 af = __builtin_bit_cast(bf16x8, cvt8u(a[cur][0], a[cur][1]));
        #pragma unroll
        for (int j = 0; j < 4; j++) acc[j] = MFMA(af, bfr[j], acc[j]);
    }
    #pragma unroll
    for (int j = 0; j < 4; j++) {
        int col = n0 + j * 16 + ln15;
        float sv = S[col], bv = Bb[col];
        #pragma unroll
        for (int r = 0; r < 4; r++) {
            int row = m0 + quad * 4 + r;
            float x = acc[j][r] + bv;
            Schi[(size_t)row * RANK + col] = f2bf_fast(sv / (1.f + __expf(-x)));
        }
    }
}

// ---- K2: T0p[z] = X@U partial. X-strip staged ONCE (read X exactly once) ----
// grid (256 m-strips of 16, 4 k-chunks of 1024) = 1024 blk x 256 thr (4 waves)
// wave (ni 2 x ki 2): tile m=16 n=128 k=512. ZSPLIT = 4*2 = 8.
__launch_bounds__(256, 4)
__global__ void k2_t0(const float* __restrict__ X, const unsigned short* __restrict__ UT,
                      unsigned short* __restrict__ T0p) {
    __shared__ unsigned short Xs[16 * 1024];  // 32 KB, swizzled 16B chunks
    int tid = threadIdx.x, wv = tid >> 6, lane = tid & 63;
    int ln15 = lane & 15, quad = lane >> 4;
    int mbase = blockIdx.x * 16;
    int kbase = blockIdx.y * 1024;
    {   // stage X strip fp32 -> bf16 LDS, coalesced, one barrier
        int r = tid >> 4, tc = tid & 15;
        const float* src = X + (size_t)(mbase + r) * N_IN + kbase;
        unsigned short* drow = Xs + r * 1024;
        #pragma unroll
        for (int s = 0; s < 8; s++) {
            int j = tc + s * 16;                // chunk 0..127
            float4 lo = *(const float4*)(src + j * 8);
            float4 hi = *(const float4*)(src + j * 8 + 4);
            *(ushort8*)(drow + ((j ^ (r & 7)) * 8)) = cvt8u(lo, hi);
        }
    }
    __syncthreads();
    int ni = wv & 1, ki = wv >> 1;              // ni<2, ki<2
    int n0 = ni * 128;
    const unsigned short* Bp = UT + (size_t)(n0 + ln15) * N_IN + kbase + ki * 512 + quad * 8;
    const unsigned short* Arow = Xs + ln15 * 1024;
    int abase = ki * 64;                        // chunk offset for this wave's k-half
    f32x4 acc[8] = {};
    ushort8 b[2][8];
    #pragma unroll
    for (int j = 0; j < 8; j++) b[0][j] = *(const ushort8*)(Bp + (size_t)j * 16 * N_IN);
    bf16x8 afc = ldfrag(Arow + (((abase + quad) ^ (ln15 & 7)) * 8));
    #pragma unroll
    for (int kt = 0; kt < 16; kt++) {
        int cur = kt & 1, nxt = cur ^ 1;
        bf16x8 afn = afc;
        if (kt < 15) {
            const unsigned short* Bp2 = Bp + (kt + 1) * 32;
            #pragma unroll
            for (int j = 0; j < 8; j++) b[nxt][j] = *(const ushort8*)(Bp2 + (size_t)j * 16 * N_IN);
            int ch = abase + (kt + 1) * 4 + quad;
            afn = ldfrag(Arow + ((ch ^ (ln15 & 7)) * 8));
        }
        #pragma unroll
        for (int j = 0; j < 8; j++)
            acc[j] = MFMA(afc, __builtin_bit_cast(bf16x8, b[cur][j]), acc[j]);
        afc = afn;
    }
    int z = blockIdx.y * 2 + ki;
    unsigned short* P = T0p + (size_t)z * B_SZ * RANK;
    #pragma unroll
    for (int j = 0; j < 8; j++) {
        int col = n0 + j * 16 + ln15;
        #pragma unroll
        for (int r = 0; r < 4; r++) {
            int row = mbase + quad * 4 + r;
            P[(size_t)row * RANK + col] = f2bf_fast(acc[j][r]);
        }
    }
}

// ---- E: T = bf16( (sum_z T0p[z]) * Schi ) ------------------------------
__global__ void e_red(const unsigned short* __restrict__ T0p, const unsigned short* __restrict__ Schi,
                      unsigned short* __restrict__ T) {
    int i = blockIdx.x * 256 + threadIdx.x;   // ushort8 index
    const size_t stride = (size_t)B_SZ * RANK;
    float a[8] = {};
    for (int z = 0; z < ZSPLIT; z++) {
        ushort8 p = *(const ushort8*)(T0p + z * stride + (size_t)i * 8);
        for (int k = 0; k < 8; k++) a[k] += bf2f(p[k]);
    }
    ushort8 s = *(const ushort8*)(Schi + (size_t)i * 8);
    ushort8 o;
    for (int k = 0; k < 8; k++) o[k] = f2bf_fast(a[k] * bf2f(s[k]));
    *(ushort8*)(T + (size_t)i * 8) = o;
}

// ---- K3: out = relu(T@V^T + 2*bias). B-LDS 32KB, grid (64,32)=2048 blk ----
// 256 thr = 4 waves; wave tile m=32 n=64, K=256
__launch_bounds__(256, 4)
__global__ void k3_out(const unsigned short* __restrict__ T, const unsigned short* __restrict__ Vb,
                       const float* __restrict__ bias, float* __restrict__ out) {
    __shared__ unsigned short Bs[64 * 256];   // 32 KB
    int tid = threadIdx.x, wv = tid >> 6, lane = tid & 63;
    int ln15 = lane & 15, quad = lane >> 4;
    int n0 = blockIdx.x * 64, mbase = blockIdx.y * 128;
    #pragma unroll
    for (int i = 0; i < 8; i++) {
        int linear = i * 256 + tid;
        int r = linear >> 5, c = linear & 31;
        ushort8 v = *(const ushort8*)(Vb + (size_t)(n0 + r) * RANK + c * 8);
        *(ushort8*)(Bs + r * 256 + ((c ^ (r & 7)) * 8)) = v;
    }
    __syncthreads();
    int m0 = mbase + wv * 32;
    const unsigned short* Ap  = T + (size_t)(m0 + ln15) * RANK + quad * 8;
    const unsigned short* Ap2 = Ap + (size_t)16 * RANK;
    f32x4 acc[2][4] = {};
    ushort8 a[2][2];
    a[0][0] = *(const ushort8*)(Ap);
    a[0][1] = *(const ushort8*)(Ap2);
    #pragma unroll
    for (int kt = 0; kt < 8; kt++) {
        int cur = kt & 1, nxt = cur ^ 1;
        if (kt < 7) {
            int ko = (kt + 1) * 32;
            a[nxt][0] = *(const ushort8*)(Ap + ko);
            a[nxt][1] = *(const ushort8*)(Ap2 + ko);
        }
        bf16x8 bfr[4];
        int sw8 = ((4 * kt + quad) ^ (ln15 & 7)) * 8;
        #pragma unroll
        for (int j = 0; j < 4; j++) bfr[j] = ldfrag(Bs + (j * 16 + ln15) * 256 + sw8);
        bf16x8 af0 = __builtin_bit_cast(bf16x8, a[cur][0]);
        bf16x8 af1 = __builtin_bit_cast(bf16x8, a[cur][1]);
        #pragma unroll
        for (int j = 0; j < 4; j++) {
            acc[0][j] = MFMA(af0, bfr[j], acc[0][j]);
            acc[1][j] = MFMA(af1, bfr[j], acc[1][j]);
        }
    }
    #pragma unroll
    for (int j = 0; j < 4; j++) {
        int col = n0 + j * 16 + ln15;
        float bv = 2.f * bias[col];
        #pragma unroll
        for (int i = 0; i < 2; i++)
            #pragma unroll
            for (int r = 0; r < 4; r++) {
                int row = m0 + i * 16 + quad * 4 + r;
                float v = acc[i][j][r] + bv;
                out[(size_t)row * UNITS + col] = fmaxf(v, 0.f);
            }
    }
}

extern "C" void kernel_launch(void* const* d_in, const int* in_sizes, int n_in,
                              void* d_out, int out_size, void* d_ws, size_t ws_size,
                              hipStream_t stream) {
    (void)in_sizes; (void)n_in; (void)out_size; (void)ws_size;
    const float* inputs  = (const float*)d_in[0];
    const float* context = (const float*)d_in[1];
    const float* U       = (const float*)d_in[2];
    const float* S       = (const float*)d_in[3];
    const float* V       = (const float*)d_in[4];
    const float* W       = (const float*)d_in[5];
    const float* Bb      = (const float*)d_in[6];
    const float* bias    = (const float*)d_in[7];
    float* out = (float*)d_out;

    char* ws = (char*)d_ws;
    size_t o = 0;
    unsigned short* UT   = (unsigned short*)(ws + o); o += (size_t)RANK * N_IN * 2;
    unsigned short* WT   = (unsigned short*)(ws + o); o += (size_t)RANK * N_CTX * 2;
    unsigned short* Vb   = (unsigned short*)(ws + o); o += (size_t)UNITS * RANK * 2;
    unsigned short* Schi = (unsigned short*)(ws + o); o += (size_t)B_SZ * RANK * 2;
    unsigned short* T    = (unsigned short*)(ws + o); o += (size_t)B_SZ * RANK * 2;
    unsigned short* T0p  = (unsigned short*)(ws + o); o += (size_t)ZSPLIT * B_SZ * RANK * 2;

    prep<<<800, 256, 0, stream>>>(U, W, V, UT, WT, Vb);
    k2_t0<<<dim3(256, 4), 256, 0, stream>>>(inputs, UT, T0p);
    k1_chi<<<dim3(4, 64), 256, 0, stream>>>(context, WT, S, Bb, Schi);
    e_red<<<(B_SZ * RANK) / (256 * 8), 256, 0, stream>>>(T0p, Schi, T);
    k3_out<<<dim3(64, 32), 256, 0, stream>>>(T, Vb, bias, out);
}

// Round 7
// 181.038 us; speedup vs baseline: 1.2457x; 1.2457x over previous
//
#include <hip/hip_runtime.h>

#define B_SZ 4096
#define N_IN 4096
#define N_CTX 512
#define UNITS 4096
#define RANK 256
#define ZSPLIT 8

typedef __attribute__((ext_vector_type(8))) __bf16 bf16x8;
typedef __attribute__((ext_vector_type(4))) float f32x4;
typedef __attribute__((ext_vector_type(8))) unsigned short ushort8;

__device__ __forceinline__ unsigned short f2bf(float f) {      // RNE (prep only)
    unsigned int u = __float_as_uint(f);
    u += 0x7FFFu + ((u >> 16) & 1u);
    return (unsigned short)(u >> 16);
}
__device__ __forceinline__ unsigned short f2bf_fast(float f) { // round-half-up, 0.5ulp
    return (unsigned short)((__float_as_uint(f) + 0x8000u) >> 16);
}
__device__ __forceinline__ float bf2f(unsigned short h) {
    return __uint_as_float(((unsigned int)h) << 16);
}
__device__ __forceinline__ void gload_lds16(const unsigned short* g, unsigned short* l) {
    __builtin_amdgcn_global_load_lds(
        (const __attribute__((address_space(1))) unsigned int*)g,
        (__attribute__((address_space(3))) unsigned int*)l, 16, 0, 0);
}
__device__ __forceinline__ bf16x8 ldfrag(const unsigned short* p) {
    ushort8 t = *(const ushort8*)p;
    return __builtin_bit_cast(bf16x8, t);
}
__device__ __forceinline__ ushort8 cvt8u(float4 lo, float4 hi) {
    ushort8 t = { f2bf_fast(lo.x), f2bf_fast(lo.y), f2bf_fast(lo.z), f2bf_fast(lo.w),
                  f2bf_fast(hi.x), f2bf_fast(hi.y), f2bf_fast(hi.z), f2bf_fast(hi.w) };
    return t;
}
#define MFMA(a, b, c) __builtin_amdgcn_mfma_f32_16x16x32_bf16((a), (b), (c), 0, 0, 0)

// ---- fused prep: U^T (bf16), W^T (bf16), V convert (bf16) --------------
__global__ void prep(const float* __restrict__ U, const float* __restrict__ W,
                     const float* __restrict__ V,
                     unsigned short* __restrict__ UT, unsigned short* __restrict__ WT,
                     unsigned short* __restrict__ Vb) {
    __shared__ unsigned short t[64][66];
    int bid = blockIdx.x, tid = threadIdx.x;
    if (bid < 288) {
        const float* src; unsigned short* dst; int R, C, rb, cb;
        if (bid < 256) { src = U; dst = UT; R = N_IN; C = RANK; rb = (bid & 63) * 64; cb = (bid >> 6) * 64; }
        else { int b = bid - 256; src = W; dst = WT; R = N_CTX; C = RANK; rb = (b & 7) * 64; cb = (b >> 3) * 64; }
        int r = tid >> 4, c4 = (tid & 15) * 4;
        for (int i = 0; i < 4; i++) {
            float4 v = *(const float4*)(src + (size_t)(rb + r + i * 16) * C + cb + c4);
            t[r + i * 16][c4 + 0] = f2bf(v.x);
            t[r + i * 16][c4 + 1] = f2bf(v.y);
            t[r + i * 16][c4 + 2] = f2bf(v.z);
            t[r + i * 16][c4 + 3] = f2bf(v.w);
        }
        __syncthreads();
        int c = tid >> 3, r8 = (tid & 7) * 8;
        for (int j = 0; j < 2; j++) {
            int cc = c + j * 32;
            ushort8 o;
            for (int k = 0; k < 8; k++) o[k] = t[r8 + k][cc];
            *(ushort8*)(dst + (size_t)(cb + cc) * R + rb + r8) = o;
        }
    } else {
        size_t base = (size_t)(bid - 288) * 2048 + (size_t)tid * 8;
        float4 a = *(const float4*)(V + base);
        float4 b = *(const float4*)(V + base + 4);
        ushort8 o = { f2bf(a.x), f2bf(a.y), f2bf(a.z), f2bf(a.w),
                      f2bf(b.x), f2bf(b.y), f2bf(b.z), f2bf(b.w) };
        *(ushort8*)(Vb + base) = o;
    }
}

// ---- K1: Schi = S*sigmoid(ctx@W+B). B-LDS resident, grid (4,64)=256 blk ----
__launch_bounds__(256, 4)
__global__ void k1_chi(const float* __restrict__ ctx, const unsigned short* __restrict__ WT,
                       const float* __restrict__ S, const float* __restrict__ Bb,
                       unsigned short* __restrict__ Schi) {
    __shared__ unsigned short Bs[64 * 512];   // 64 KB
    int tid = threadIdx.x, wv = tid >> 6, lane = tid & 63;
    int ln15 = lane & 15, quad = lane >> 4;
    int n0 = blockIdx.x * 64, mbase = blockIdx.y * 64;
    #pragma unroll
    for (int i = 0; i < 16; i++) {
        int linear = i * 256 + tid;
        int r = linear >> 6, c = linear & 63;
        ushort8 v = *(const ushort8*)(WT + (size_t)(n0 + r) * N_CTX + c * 8);
        *(ushort8*)(Bs + r * 512 + ((c ^ (r & 7)) * 8)) = v;
    }
    __syncthreads();
    int m0 = mbase + wv * 16;
    const float* Xp = ctx + (size_t)(m0 + ln15) * N_CTX + quad * 8;
    f32x4 acc[4] = {};
    float4 a[2][2];
    a[0][0] = *(const float4*)(Xp); a[0][1] = *(const float4*)(Xp + 4);
    #pragma unroll
    for (int kt = 0; kt < 16; kt++) {
        int cur = kt & 1, nxt = cur ^ 1;
        if (kt < 15) {
            int ko = (kt + 1) * 32;
            a[nxt][0] = *(const float4*)(Xp + ko); a[nxt][1] = *(const float4*)(Xp + ko + 4);
        }
        bf16x8 bfr[4];
        int sw8 = ((4 * kt + quad) ^ (ln15 & 7)) * 8;
        #pragma unroll
        for (int j = 0; j < 4; j++) bfr[j] = ldfrag(Bs + (j * 16 + ln15) * 512 + sw8);
        bf16x8 af = __builtin_bit_cast(bf16x8, cvt8u(a[cur][0], a[cur][1]));
        #pragma unroll
        for (int j = 0; j < 4; j++) acc[j] = MFMA(af, bfr[j], acc[j]);
    }
    #pragma unroll
    for (int j = 0; j < 4; j++) {
        int col = n0 + j * 16 + ln15;
        float sv = S[col], bv = Bb[col];
        #pragma unroll
        for (int r = 0; r < 4; r++) {
            int row = m0 + quad * 4 + r;
            float x = acc[j][r] + bv;
            Schi[(size_t)row * RANK + col] = f2bf_fast(sv / (1.f + __expf(-x)));
        }
    }
}

// ---- K2: T0p[z] = X@U partial. n=256 full (X read ONCE), B dbuf-LDS ------
// grid (64 m-strips of 64, 8 z-chunks of 512) = 512 blk x 256 thr (4 waves)
// wave tile m=16 n=256; BK=64, 8 iters, barrier-at-top pipeline
__launch_bounds__(256, 2)
__global__ void k2_t0(const float* __restrict__ X, const unsigned short* __restrict__ UT,
                      unsigned short* __restrict__ T0p) {
    __shared__ __align__(16) unsigned short Bs[2][256 * 64];   // 2 x 32 KB
    int tid = threadIdx.x, wv = tid >> 6, lane = tid & 63;
    int ln15 = lane & 15, quad = lane >> 4;
    int mbase = blockIdx.x * 64;
    int z = blockIdx.y;
    int kbase = z * 512;
    const float* Xp = X + (size_t)(mbase + wv * 16 + ln15) * N_IN + kbase + quad * 8;

    // prologue: stage kt=0 -> buf0; load A(0)
    #pragma unroll
    for (int i = 0; i < 8; i++) {
        int linear = i * 256 + tid;
        int r = linear >> 3, cs = linear & 7;
        int gc = cs ^ (r & 7);
        gload_lds16(UT + (size_t)r * N_IN + kbase + gc * 8, &Bs[0][linear * 8]);
    }
    float4 a[2][2][2];
    #pragma unroll
    for (int kh = 0; kh < 2; kh++) {
        a[0][kh][0] = *(const float4*)(Xp + kh * 32);
        a[0][kh][1] = *(const float4*)(Xp + kh * 32 + 4);
    }
    f32x4 acc[16] = {};
    #pragma unroll
    for (int kt = 0; kt < 8; kt++) {
        int cur = kt & 1, nxt = cur ^ 1;
        __syncthreads();                    // buf[cur] ready; staged during prev compute
        if (kt < 7) {
            int k0 = (kt + 1) * 64;
            #pragma unroll
            for (int i = 0; i < 8; i++) {
                int linear = i * 256 + tid;
                int r = linear >> 3, cs = linear & 7;
                int gc = cs ^ (r & 7);
                gload_lds16(UT + (size_t)r * N_IN + kbase + k0 + gc * 8, &Bs[nxt][linear * 8]);
            }
            #pragma unroll
            for (int kh = 0; kh < 2; kh++) {
                a[nxt][kh][0] = *(const float4*)(Xp + k0 + kh * 32);
                a[nxt][kh][1] = *(const float4*)(Xp + k0 + kh * 32 + 4);
            }
        }
        #pragma unroll
        for (int kh = 0; kh < 2; kh++) {
            bf16x8 af = __builtin_bit_cast(bf16x8, cvt8u(a[cur][kh][0], a[cur][kh][1]));
            int g = kh * 4 + quad;
            int sw8 = (g ^ (ln15 & 7)) * 8;
            #pragma unroll
            for (int j = 0; j < 16; j++) {
                bf16x8 bfr = ldfrag(&Bs[cur][(j * 16 + ln15) * 64 + sw8]);
                acc[j] = MFMA(af, bfr, acc[j]);
            }
        }
    }
    unsigned short* P = T0p + (size_t)z * B_SZ * RANK + (size_t)(mbase + wv * 16) * RANK;
    #pragma unroll
    for (int j = 0; j < 16; j++) {
        int col = j * 16 + ln15;
        #pragma unroll
        for (int r = 0; r < 4; r++) {
            int row = quad * 4 + r;
            P[(size_t)row * RANK + col] = f2bf_fast(acc[j][r]);
        }
    }
}

// ---- E: T = bf16( (sum_z T0p[z]) * Schi ) ------------------------------
__global__ void e_red(const unsigned short* __restrict__ T0p, const unsigned short* __restrict__ Schi,
                      unsigned short* __restrict__ T) {
    int i = blockIdx.x * 256 + threadIdx.x;   // ushort8 index
    const size_t stride = (size_t)B_SZ * RANK;
    float a[8] = {};
    for (int z = 0; z < ZSPLIT; z++) {
        ushort8 p = *(const ushort8*)(T0p + z * stride + (size_t)i * 8);
        for (int k = 0; k < 8; k++) a[k] += bf2f(p[k]);
    }
    ushort8 s = *(const ushort8*)(Schi + (size_t)i * 8);
    ushort8 o;
    for (int k = 0; k < 8; k++) o[k] = f2bf_fast(a[k] * bf2f(s[k]));
    *(ushort8*)(T + (size_t)i * 8) = o;
}

// ---- K3: out = relu(T@V^T + 2*bias). B-LDS 32KB, grid (64,32)=2048 blk ----
__launch_bounds__(256, 4)
__global__ void k3_out(const unsigned short* __restrict__ T, const unsigned short* __restrict__ Vb,
                       const float* __restrict__ bias, float* __restrict__ out) {
    __shared__ unsigned short Bs[64 * 256];   // 32 KB
    int tid = threadIdx.x, wv = tid >> 6, lane = tid & 63;
    int ln15 = lane & 15, quad = lane >> 4;
    int n0 = blockIdx.x * 64, mbase = blockIdx.y * 128;
    #pragma unroll
    for (int i = 0; i < 8; i++) {
        int linear = i * 256 + tid;
        int r = linear >> 5, c = linear & 31;
        ushort8 v = *(const ushort8*)(Vb + (size_t)(n0 + r) * RANK + c * 8);
        *(ushort8*)(Bs + r * 256 + ((c ^ (r & 7)) * 8)) = v;
    }
    __syncthreads();
    int m0 = mbase + wv * 32;
    const unsigned short* Ap  = T + (size_t)(m0 + ln15) * RANK + quad * 8;
    const unsigned short* Ap2 = Ap + (size_t)16 * RANK;
    f32x4 acc[2][4] = {};
    ushort8 a[2][2];
    a[0][0] = *(const ushort8*)(Ap);
    a[0][1] = *(const ushort8*)(Ap2);
    #pragma unroll
    for (int kt = 0; kt < 8; kt++) {
        int cur = kt & 1, nxt = cur ^ 1;
        if (kt < 7) {
            int ko = (kt + 1) * 32;
            a[nxt][0] = *(const ushort8*)(Ap + ko);
            a[nxt][1] = *(const ushort8*)(Ap2 + ko);
        }
        bf16x8 bfr[4];
        int sw8 = ((4 * kt + quad) ^ (ln15 & 7)) * 8;
        #pragma unroll
        for (int j = 0; j < 4; j++) bfr[j] = ldfrag(Bs + (j * 16 + ln15) * 256 + sw8);
        bf16x8 af0 = __builtin_bit_cast(bf16x8, a[cur][0]);
        bf16x8 af1 = __builtin_bit_cast(bf16x8, a[cur][1]);
        #pragma unroll
        for (int j = 0; j < 4; j++) {
            acc[0][j] = MFMA(af0, bfr[j], acc[0][j]);
            acc[1][j] = MFMA(af1, bfr[j], acc[1][j]);
        }
    }
    #pragma unroll
    for (int j = 0; j < 4; j++) {
        int col = n0 + j * 16 + ln15;
        float bv = 2.f * bias[col];
        #pragma unroll
        for (int i = 0; i < 2; i++)
            #pragma unroll
            for (int r = 0; r < 4; r++) {
                int row = m0 + i * 16 + quad * 4 + r;
                float v = acc[i][j][r] + bv;
                out[(size_t)row * UNITS + col] = fmaxf(v, 0.f);
            }
    }
}

extern "C" void kernel_launch(void* const* d_in, const int* in_sizes, int n_in,
                              void* d_out, int out_size, void* d_ws, size_t ws_size,
                              hipStream_t stream) {
    (void)in_sizes; (void)n_in; (void)out_size; (void)ws_size;
    const float* inputs  = (const float*)d_in[0];
    const float* context = (const float*)d_in[1];
    const float* U       = (const float*)d_in[2];
    const float* S       = (const float*)d_in[3];
    const float* V       = (const float*)d_in[4];
    const float* W       = (const float*)d_in[5];
    const float* Bb      = (const float*)d_in[6];
    const float* bias    = (const float*)d_in[7];
    float* out = (float*)d_out;

    char* ws = (char*)d_ws;
    size_t o = 0;
    unsigned short* UT   = (unsigned short*)(ws + o); o += (size_t)RANK * N_IN * 2;
    unsigned short* WT   = (unsigned short*)(ws + o); o += (size_t)RANK * N_CTX * 2;
    unsigned short* Vb   = (unsigned short*)(ws + o); o += (size_t)UNITS * RANK * 2;
    unsigned short* Schi = (unsigned short*)(ws + o); o += (size_t)B_SZ * RANK * 2;
    unsigned short* T    = (unsigned short*)(ws + o); o += (size_t)B_SZ * RANK * 2;
    unsigned short* T0p  = (unsigned short*)(ws + o); o += (size_t)ZSPLIT * B_SZ * RANK * 2;

    prep<<<800, 256, 0, stream>>>(U, W, V, UT, WT, Vb);
    k2_t0<<<dim3(64, 8), 256, 0, stream>>>(inputs, UT, T0p);
    k1_chi<<<dim3(4, 64), 256, 0, stream>>>(context, WT, S, Bb, Schi);
    e_red<<<(B_SZ * RANK) / (256 * 8), 256, 0, stream>>>(T0p, Schi, T);
    k3_out<<<dim3(64, 32), 256, 0, stream>>>(T, Vb, bias, out);
}